// Round 12
// baseline (167.469 us; speedup 1.0000x reference)
//
#include <hip/hip_runtime.h>

#define Bn 128
#define Hn 28
#define Wn 28
#define Cn 512
#define Pn (Hn * Wn)      // 784 spatial positions
#define SCH 8             // spatial chunks for argmax parallelism
#define PCH (Pn / SCH)    // 98 positions per chunk
#define PPB 56            // p per block in mask kernel (784 = 14*56)
#define PPT 28            // p per thread (half-block)

// Native vector type for __builtin_nontemporal_store.
typedef float f4 __attribute__((ext_vector_type(4)));

__device__ __forceinline__ void nt_store4(float* p, float a, float b, float c, float d) {
    f4 v = {a, b, c, d};
    __builtin_nontemporal_store(v, reinterpret_cast<f4*>(p));
}

// ---------------------------------------------------------------------------
// Kernel 1 (R5's proven k1): argmax partials FUSED with o1 = x copy.
// Read 205 MB + NT-write 205 MB -> balanced 410 MB stream kernel.
// Thread owns 4 consecutive c over one 98-p chunk; wave ops 1 KB contiguous;
// blocks stream full 2 KB rows sequentially in p.
// ---------------------------------------------------------------------------
__global__ void argmax_partial_copy(const float* __restrict__ x,
                                    float* __restrict__ o1,
                                    uint2* __restrict__ part) {
    int s = blockIdx.x & (SCH - 1);
    int b = blockIdx.x >> 3;
    int c0 = threadIdx.x * 4;

    size_t base = (size_t)b * Pn * Cn + c0;
    int p0 = s * PCH;

    float b0 = -INFINITY, b1 = -INFINITY, b2 = -INFINITY, b3 = -INFINITY;
    int i0 = p0, i1 = p0, i2 = p0, i3 = p0;
#pragma unroll 7
    for (int i = 0; i < PCH; ++i) {
        size_t off = base + (size_t)(p0 + i) * Cn;
        float4 v = *reinterpret_cast<const float4*>(x + off);
        nt_store4(o1 + off, v.x, v.y, v.z, v.w);
        if (v.x > b0) { b0 = v.x; i0 = p0 + i; }
        if (v.y > b1) { b1 = v.y; i1 = p0 + i; }
        if (v.z > b2) { b2 = v.z; i2 = p0 + i; }
        if (v.w > b3) { b3 = v.w; i3 = p0 + i; }
    }
    // [s][b][c] layout; 32 B/thread contiguous, written as two dwordx4.
    uint4* o = reinterpret_cast<uint4*>(part + ((size_t)s * Bn + b) * Cn + c0);
    o[0] = make_uint4(__float_as_uint(b0), (unsigned)i0,
                      __float_as_uint(b1), (unsigned)i1);
    o[1] = make_uint4(__float_as_uint(b2), (unsigned)i2,
                      __float_as_uint(b3), (unsigned)i3);
}

// ---------------------------------------------------------------------------
// Kernel 2: inline partial-fold (R11-proven, saves a dispatch) + mask pass.
//   threads 0..127 fold the 8 chunk partials (ascending s = ascending p,
//   strict > -> exact np.argmax first-max) for 4 channels each into LDS;
//   then all 256 threads: re-read x with REGULAR cacheable loads (R11 A/B
//   winner), gather 4 template rows per-lane-sequential (t_p L2-resident),
//   NT-store o0 = relu(x*t) and o2 = t. 620 MB stream kernel.
// ---------------------------------------------------------------------------
__global__ void mask_outputs(const float* __restrict__ x,
                             const float* __restrict__ tp,
                             const uint2* __restrict__ part,
                             float* __restrict__ o0,
                             float* __restrict__ o2) {
    __shared__ int sidx[Cn];

    int pc = blockIdx.x % 14;
    int b  = blockIdx.x / 14;
    int t  = threadIdx.x;

    if (t < 128) {
        int c0 = t * 4;
        const uint2* pp = part + (size_t)b * Cn + c0;
        float v0 = -INFINITY, v1 = -INFINITY, v2 = -INFINITY, v3 = -INFINITY;
        int j0 = 0, j1 = 0, j2 = 0, j3 = 0;
#pragma unroll
        for (int s = 0; s < SCH; ++s) {
            const uint2* q = pp + (size_t)s * (Bn * Cn);
            uint4 a = *reinterpret_cast<const uint4*>(q);      // (v0,i0,v1,i1)
            uint4 c = *reinterpret_cast<const uint4*>(q + 2);  // (v2,i2,v3,i3)
            float f0 = __uint_as_float(a.x), f1 = __uint_as_float(a.z);
            float f2 = __uint_as_float(c.x), f3 = __uint_as_float(c.z);
            if (f0 > v0) { v0 = f0; j0 = (int)a.y; }
            if (f1 > v1) { v1 = f1; j1 = (int)a.w; }
            if (f2 > v2) { v2 = f2; j2 = (int)c.y; }
            if (f3 > v3) { v3 = f3; j3 = (int)c.w; }
        }
        sidx[c0 + 0] = j0;
        sidx[c0 + 1] = j1;
        sidx[c0 + 2] = j2;
        sidx[c0 + 3] = j3;
    }
    __syncthreads();

    int ci = t & 127;
    int c0 = ci * 4;
    int ph = t >> 7;
    int p0 = pc * PPB + ph * PPT;

    int4 iv = *reinterpret_cast<const int4*>(sidx + c0);
    const float* t0p = tp + (size_t)iv.x * Pn;
    const float* t1p = tp + (size_t)iv.y * Pn;
    const float* t2p = tp + (size_t)iv.z * Pn;
    const float* t3p = tp + (size_t)iv.w * Pn;

    size_t xbase = (size_t)b * Pn * Cn + c0;

#pragma unroll
    for (int j = 0; j < PPT; j += 4) {
        int p = p0 + j;
        // 4 template rows, 4 consecutive p each (per-lane sequential, L2-hot)
        float4 ta = *reinterpret_cast<const float4*>(t0p + p);
        float4 tb = *reinterpret_cast<const float4*>(t1p + p);
        float4 tc = *reinterpret_cast<const float4*>(t2p + p);
        float4 td = *reinterpret_cast<const float4*>(t3p + p);
        // x re-read: regular cacheable loads (R11 A/B winner).
        float4 x0 = *reinterpret_cast<const float4*>(x + xbase + (size_t)(p + 0) * Cn);
        float4 x1 = *reinterpret_cast<const float4*>(x + xbase + (size_t)(p + 1) * Cn);
        float4 x2 = *reinterpret_cast<const float4*>(x + xbase + (size_t)(p + 2) * Cn);
        float4 x3 = *reinterpret_cast<const float4*>(x + xbase + (size_t)(p + 3) * Cn);

        size_t q0 = xbase + (size_t)(p + 0) * Cn;
        size_t q1 = xbase + (size_t)(p + 1) * Cn;
        size_t q2 = xbase + (size_t)(p + 2) * Cn;
        size_t q3 = xbase + (size_t)(p + 3) * Cn;

        // o0 = relu(x * t)
        nt_store4(o0 + q0, fmaxf(x0.x * ta.x, 0.f), fmaxf(x0.y * tb.x, 0.f),
                           fmaxf(x0.z * tc.x, 0.f), fmaxf(x0.w * td.x, 0.f));
        nt_store4(o0 + q1, fmaxf(x1.x * ta.y, 0.f), fmaxf(x1.y * tb.y, 0.f),
                           fmaxf(x1.z * tc.y, 0.f), fmaxf(x1.w * td.y, 0.f));
        nt_store4(o0 + q2, fmaxf(x2.x * ta.z, 0.f), fmaxf(x2.y * tb.z, 0.f),
                           fmaxf(x2.z * tc.z, 0.f), fmaxf(x2.w * td.z, 0.f));
        nt_store4(o0 + q3, fmaxf(x3.x * ta.w, 0.f), fmaxf(x3.y * tb.w, 0.f),
                           fmaxf(x3.z * tc.w, 0.f), fmaxf(x3.w * td.w, 0.f));
        // o2 = templates
        nt_store4(o2 + q0, ta.x, tb.x, tc.x, td.x);
        nt_store4(o2 + q1, ta.y, tb.y, tc.y, td.y);
        nt_store4(o2 + q2, ta.z, tb.z, tc.z, td.z);
        nt_store4(o2 + q3, ta.w, tb.w, tc.w, td.w);
    }
}

extern "C" void kernel_launch(void* const* d_in, const int* in_sizes, int n_in,
                              void* d_out, int out_size, void* d_ws, size_t ws_size,
                              hipStream_t stream) {
    const float* x  = (const float*)d_in[0];   // [B,H,W,C] fp32
    const float* tp = (const float*)d_in[1];   // [H,W,H,W] fp32

    const size_t N = (size_t)Bn * Pn * Cn;
    float* o0 = (float*)d_out;                 // masked
    float* o1 = o0 + N;                        // x copy
    float* o2 = o0 + 2 * N;                    // templates

    uint2* part = (uint2*)d_ws;                // [SCH][Bn][Cn] uint2 = 4.19 MB

    argmax_partial_copy<<<Bn * SCH, 128, 0, stream>>>(x, o1, part);
    mask_outputs<<<Bn * 14, 256, 0, stream>>>(x, tp, part, o0, o2);
}